// Round 1
// 222.777 us; speedup vs baseline: 1.1441x; 1.1441x over previous
//
#include <hip/hip_runtime.h>
#include <math.h>

#define TT  34   // seq len
#define VV  14   // vocab
#define BLK 256  // threads per block

#if __has_builtin(__builtin_amdgcn_exp2f)
#define EXP2F(x) __builtin_amdgcn_exp2f(x)
#else
#define EXP2F(x) exp2f(x)
#endif

// Weight-staging LDS offsets (floats):
//  0..35  out_w (6x6)      36..41 ln2_g   42..47 ln2_b
// 48..65  ffn_w1 (3x6)     66..68 ffn_b1
// 69..86  ffn_w2 (6x3)     87..92 ffn_b2
// 93..98  lnf_g            99..104 lnf_b
// 105..188 M[v][d] = sum_c head_w[c][d]*tok_emb[v][c]   (fused head_w.T @ tok_emb.T)
// 192..233 tok_emb (14x3)  234..335 pos_enc (34x3)

__global__ __launch_bounds__(BLK) void addtx_fwd(
    const int*   __restrict__ idx,
    const float* __restrict__ tok_emb,
    const float* __restrict__ pos_enc,
    const float* __restrict__ q_w,
    const float* __restrict__ k_w,
    const float* __restrict__ v_w,
    const float* __restrict__ out_w,
    const float* __restrict__ ln1_g, const float* __restrict__ ln1_b,
    const float* __restrict__ ln2_g, const float* __restrict__ ln2_b,
    const float* __restrict__ lnf_g, const float* __restrict__ lnf_b,
    const float* __restrict__ ffn_w1, const float* __restrict__ ffn_b1,
    const float* __restrict__ ffn_w2, const float* __restrict__ ffn_b2,
    const float* __restrict__ head_w,
    float* __restrict__ out)
{
    // kvs: per (pos,tok): k0..3 | k4,k5,v0,v1 | v2..5  (k pre-scaled 1/sqrt(3)*log2e)
    // After attention it is reused as the logits staging buffer (14336B < 22848B).
    __shared__ float4 kvs[TT * VV * 3];   // 22848 B
    __shared__ float  wsm[336];           // epilogue weights + fused head matrix + emb tables
    __shared__ int    idsb[308];          // this block's token ids (<=9 rows x 34, +pad)

    const int tid = threadIdx.x;
    const int blk = blockIdx.x;

    // ---------------- stage epilogue weights + emb tables ----------------
    {
        const int i = tid;
        if (i < 36)       wsm[i] = out_w[i];
        else if (i < 42)  wsm[i] = ln2_g[i - 36];
        else if (i < 48)  wsm[i] = ln2_b[i - 42];
        else if (i < 66)  wsm[i] = ffn_w1[i - 48];
        else if (i < 69)  wsm[i] = ffn_b1[i - 66];
        else if (i < 87)  wsm[i] = ffn_w2[i - 69];
        else if (i < 93)  wsm[i] = ffn_b2[i - 87];
        else if (i < 99)  wsm[i] = lnf_g[i - 93];
        else if (i < 105) wsm[i] = lnf_b[i - 99];
        else if (i < 189) {
            const int j = i - 105, v = j / 6, d = j - v * 6;
            wsm[i] = head_w[0 * 6 + d] * tok_emb[v * 3 + 0]
                   + head_w[1 * 6 + d] * tok_emb[v * 3 + 1]
                   + head_w[2 * 6 + d] * tok_emb[v * 3 + 2];
        }
        if (tid < 144) {
            const int k2 = 192 + tid;
            wsm[k2] = (k2 < 234) ? tok_emb[k2 - 192] : pos_enc[k2 - 234];
        }
    }

    // ---------------- stage this block's token ids (coalesced) ----------------
    const int ntot = (int)gridDim.x * BLK;
    const int b0   = (blk * BLK) / TT;
    {
        const int gb = b0 * TT;
        for (int e = tid; e < 308; e += BLK) {
            const int g = gb + e;
            idsb[e] = (g < ntot) ? idx[g] : 0;
        }
    }

    // ---------------- build (pos,tok) -> k,v table ----------------
    // k pre-scaled by 1/sqrt(3) * log2(e) so the score feeds v_exp_f32 directly.
    const float rs3l = 0.57735026918962576f * 1.4426950408889634f;
    for (int e = tid; e < TT * VV; e += BLK) {
        const int pos = e / VV, id = e - pos * VV;
        float x[6];
        x[0] = tok_emb[id * 3 + 0]; x[1] = tok_emb[id * 3 + 1]; x[2] = tok_emb[id * 3 + 2];
        x[3] = pos_enc[pos * 3 + 0]; x[4] = pos_enc[pos * 3 + 1]; x[5] = pos_enc[pos * 3 + 2];
        float mu = (x[0] + x[1] + x[2] + x[3] + x[4] + x[5]) * (1.0f / 6.0f);
        float var = 0.0f;
        #pragma unroll
        for (int d = 0; d < 6; ++d) { float dd = x[d] - mu; var += dd * dd; }
        const float rstd = rsqrtf(var * (1.0f / 6.0f) + 1e-5f);
        float h[6];
        #pragma unroll
        for (int d = 0; d < 6; ++d) h[d] = (x[d] - mu) * rstd * ln1_g[d] + ln1_b[d];
        float kk[6], vvv[6];
        #pragma unroll
        for (int r = 0; r < 6; ++r) {
            kk[r]  = (h[3] * k_w[r * 3 + 0] + h[4] * k_w[r * 3 + 1] + h[5] * k_w[r * 3 + 2]) * rs3l;
            vvv[r] =  h[0] * v_w[r * 3 + 0] + h[1] * v_w[r * 3 + 1] + h[2] * v_w[r * 3 + 2];
        }
        kvs[e * 3 + 0] = make_float4(kk[0], kk[1], kk[2], kk[3]);
        kvs[e * 3 + 1] = make_float4(kk[4], kk[5], vvv[0], vvv[1]);
        kvs[e * 3 + 2] = make_float4(vvv[2], vvv[3], vvv[4], vvv[5]);
    }
    __syncthreads();

    // ---------------- t-balanced intra-block remap (closed form) ----------------
    // Groups assigned in tau order, dlt=(tau-r0)%34, group size c(dlt)=8 if dlt<18 else 7.
    // Sequence of dlt is the rotation starting at m=(34-r0)%34; cumulative sums are
    // piecewise-linear -> 3-way segment select instead of a 34-iteration search.
    const int srank = (tid + ((blk & 3) << 6)) & (BLK - 1);
    const int r0 = (blk * BLK) % TT;
    const int m  = (TT - r0) % TT;
    int dsel, ksel;
    if (m < 18) {
        // [m..17]x8, [18..33]x7, [0..m-1]x8
        const int nA = (18 - m) << 3;
        if (srank < nA)            { dsel = m + (srank >> 3); ksel = srank & 7; }
        else if (srank < nA + 112) { const int r = srank - nA;       dsel = 18 + r / 7; ksel = r % 7; }
        else                       { const int r = srank - nA - 112; dsel = r >> 3;     ksel = r & 7; }
    } else {
        // [m..33]x7, [0..17]x8, [18..m-1]x7
        const int nA = (TT - m) * 7;
        if (srank < nA)            { dsel = m + srank / 7; ksel = srank % 7; }
        else if (srank < nA + 144) { const int r = srank - nA;       dsel = r >> 3;     ksel = r & 7; }
        else                       { const int r = srank - nA - 144; dsel = 18 + r / 7; ksel = r % 7; }
    }
    const int il   = dsel + ksel * TT;       // local slot in [0,256), bijection of tid
    const int flat = blk * BLK + il;
    const int b    = flat / TT;
    const int t    = flat - b * TT;
    const int* __restrict__ rowL = idsb + (b - b0) * TT;   // LDS-resident row

    // ---------------- own x (pre-LN residual) and q ----------------
    float x[6];
    {
        const int mid = rowL[t];
        x[0] = wsm[192 + mid * 3]; x[1] = wsm[193 + mid * 3]; x[2] = wsm[194 + mid * 3];
        x[3] = wsm[234 + t * 3];   x[4] = wsm[235 + t * 3];   x[5] = wsm[236 + t * 3];
    }
    float q[6];
    {
        float mu = (x[0] + x[1] + x[2] + x[3] + x[4] + x[5]) * (1.0f / 6.0f);
        float var = 0.0f;
        #pragma unroll
        for (int d = 0; d < 6; ++d) { float dd = x[d] - mu; var += dd * dd; }
        const float rstd = rsqrtf(var * (1.0f / 6.0f) + 1e-5f);
        float h[6];
        #pragma unroll
        for (int d = 0; d < 6; ++d) h[d] = (x[d] - mu) * rstd * ln1_g[d] + ln1_b[d];
        #pragma unroll
        for (int r = 0; r < 6; ++r)
            q[r] = h[3] * q_w[r * 3 + 0] + h[4] * q_w[r * 3 + 1] + h[5] * q_w[r * 3 + 2];
    }

    // ---------------- causal attention, exp-sum softmax ----------------
    // Scores bounded (LN output * uniform-init weights), so plain exp-sum == softmax
    // exactly in fp32. k carries the log2e scale -> EXP2F is a single v_exp_f32.
    // ids prefetched one iteration ahead from LDS to break the load->addr->load chain.
    float l0 = 0.f, l1 = 0.f;
    float a0 = 0.f, a1 = 0.f, a2 = 0.f, a3 = 0.f, a4 = 0.f, a5 = 0.f;
    int ids = rowL[0];
    int sb = 0;
    for (int s = 0; s <= t; ++s) {
        const float4* e4 = kvs + (sb + ids * 3);
        const float4 ka = e4[0];
        const float4 kb = e4[1];
        const float4 vb = e4[2];
        ids = rowL[s + 1];                       // prefetch (padded, safe at s==t)
        const float sc0 = q[0] * ka.x + q[1] * ka.y + q[2] * ka.z;
        const float sc1 = q[3] * ka.w + q[4] * kb.x + q[5] * kb.y;
        const float p0 = EXP2F(sc0);
        const float p1 = EXP2F(sc1);
        l0 += p0; l1 += p1;
        a0 += p0 * kb.z; a1 += p0 * kb.w; a2 += p0 * vb.x;
        a3 += p1 * vb.y; a4 += p1 * vb.z; a5 += p1 * vb.w;
        sb += VV * 3;
    }
    const float i0 = 1.0f / l0, i1 = 1.0f / l1;
    const float o6[6] = { a0 * i0, a1 * i0, a2 * i0, a3 * i1, a4 * i1, a5 * i1 };

    // ---------------- residual + out proj ----------------
    #pragma unroll
    for (int d = 0; d < 6; ++d) {
        float s = x[d];
        #pragma unroll
        for (int j = 0; j < 6; ++j) s += o6[j] * wsm[d * 6 + j];
        x[d] = s;
    }

    // ---------------- LN2 + FFN (exact gelu) + residual ----------------
    {
        float mu = (x[0] + x[1] + x[2] + x[3] + x[4] + x[5]) * (1.0f / 6.0f);
        float var = 0.0f;
        #pragma unroll
        for (int d = 0; d < 6; ++d) { float dd = x[d] - mu; var += dd * dd; }
        const float rstd = rsqrtf(var * (1.0f / 6.0f) + 1e-5f);
        float h2[6];
        #pragma unroll
        for (int d = 0; d < 6; ++d) h2[d] = (x[d] - mu) * rstd * wsm[36 + d] + wsm[42 + d];
        float g3[3];
        #pragma unroll
        for (int i = 0; i < 3; ++i) {
            float f = wsm[66 + i];
            #pragma unroll
            for (int d = 0; d < 6; ++d) f += h2[d] * wsm[48 + i * 6 + d];
            g3[i] = 0.5f * f * (1.0f + erff(f * 0.70710678118654752f));
        }
        #pragma unroll
        for (int d = 0; d < 6; ++d) {
            float s = x[d] + wsm[87 + d];
            #pragma unroll
            for (int i = 0; i < 3; ++i) s += g3[i] * wsm[69 + d * 3 + i];
            x[d] = s;
        }
    }

    // ---------------- LNF + fused head (logits to registers) ----------------
    float lg[VV];
    {
        float mu = (x[0] + x[1] + x[2] + x[3] + x[4] + x[5]) * (1.0f / 6.0f);
        float var = 0.0f;
        #pragma unroll
        for (int d = 0; d < 6; ++d) { float dd = x[d] - mu; var += dd * dd; }
        const float rstd = rsqrtf(var * (1.0f / 6.0f) + 1e-5f);
        float xf[6];
        #pragma unroll
        for (int d = 0; d < 6; ++d) xf[d] = (x[d] - mu) * rstd * wsm[93 + d] + wsm[99 + d];
        #pragma unroll
        for (int v = 0; v < VV; ++v) {
            float s = 0.0f;
            #pragma unroll
            for (int d = 0; d < 6; ++d) s += xf[d] * wsm[105 + v * 6 + d];
            lg[v] = s;
        }
    }

    // ---------------- stage logits over kvs (now dead) + coalesced writeout ----------------
    __syncthreads();                        // all threads done reading kvs
    float2* lg2 = reinterpret_cast<float2*>(kvs);
    #pragma unroll
    for (int j = 0; j < 7; ++j)
        lg2[il * 7 + j] = make_float2(lg[2 * j], lg[2 * j + 1]);
    __syncthreads();
    const float2* s2 = reinterpret_cast<const float2*>(kvs);
    float2* __restrict__ ob2 = reinterpret_cast<float2*>(out + (size_t)blk * (BLK * VV));
    #pragma unroll
    for (int j = 0; j < 7; ++j)
        ob2[j * BLK + tid] = s2[j * BLK + tid];
}

extern "C" void kernel_launch(void* const* d_in, const int* in_sizes, int n_in,
                              void* d_out, int out_size, void* d_ws, size_t ws_size,
                              hipStream_t stream) {
    const int*   idx     = (const int*)  d_in[0];
    const float* tok_emb = (const float*)d_in[1];
    const float* pos_enc = (const float*)d_in[2];
    const float* q_w     = (const float*)d_in[3];
    const float* k_w     = (const float*)d_in[4];
    const float* v_w     = (const float*)d_in[5];
    const float* out_w   = (const float*)d_in[6];
    const float* ln1_g   = (const float*)d_in[7];
    const float* ln1_b   = (const float*)d_in[8];
    const float* ln2_g   = (const float*)d_in[9];
    const float* ln2_b   = (const float*)d_in[10];
    const float* lnf_g   = (const float*)d_in[11];
    const float* lnf_b   = (const float*)d_in[12];
    const float* ffn_w1  = (const float*)d_in[13];
    const float* ffn_b1  = (const float*)d_in[14];
    const float* ffn_w2  = (const float*)d_in[15];
    const float* ffn_b2  = (const float*)d_in[16];
    const float* head_w  = (const float*)d_in[17];
    float* out = (float*)d_out;

    const int n = in_sizes[0];        // B*T = 65536*34 = 2228224, divisible by 256
    const int blocks = n / BLK;       // 8704
    addtx_fwd<<<blocks, BLK, 0, stream>>>(idx, tok_emb, pos_enc, q_w, k_w, v_w, out_w,
                                          ln1_g, ln1_b, ln2_g, ln2_b, lnf_g, lnf_b,
                                          ffn_w1, ffn_b1, ffn_w2, ffn_b2, head_w, out);
}